// Round 1
// baseline (2398.219 us; speedup 1.0000x reference)
//
#include <hip/hip_runtime.h>
#include <stdint.h>

// Problem constants
constexpr int cB = 4096;   // batch
constexpr int cF = 4096;   // feat dim
constexpr int cH = 1024;   // enc hidden
constexpr int cL = 512;    // latent
constexpr int cK = 8192;   // codebook size

// ---------------------------------------------------------------------------
// Generic fp32 tiled GEMM: C = epi(A@B + bias), optional B-row scale (bscale[k])
// and output-row scale (rowscale[i]).
// BM=BN=64, BK=16, 256 threads, 4x4 microtile per thread.
// EPI: 0=none, 1=relu, 2=sigmoid, 3=(x+1)*0.5
// BT: B stored [N,Kd] row-major (we need B^T)
// ---------------------------------------------------------------------------
template<int EPI, bool BT, bool BSC, bool RSC>
__global__ __launch_bounds__(256)
void gemm_f32(const float* __restrict__ A, const float* __restrict__ Bm,
              const float* __restrict__ bias,
              const float* __restrict__ bscale, const float* __restrict__ rowscale,
              float* __restrict__ C, int M, int N, int Kd) {
    __shared__ float As[16][68];
    __shared__ float Bs[16][68];
    const int tid = threadIdx.x;
    const int tx = tid & 15, ty = tid >> 4;
    const int row0 = blockIdx.y * 64, col0 = blockIdx.x * 64;
    float acc[4][4] = {};

    for (int k0 = 0; k0 < Kd; k0 += 16) {
        // A tile: 64 rows x 16 k, one float4 along k per thread
        {
            int r = tid >> 2, kk = (tid & 3) * 4;
            float4 av = *(const float4*)(A + (size_t)(row0 + r) * Kd + k0 + kk);
            As[kk + 0][r] = av.x; As[kk + 1][r] = av.y;
            As[kk + 2][r] = av.z; As[kk + 3][r] = av.w;
        }
        if (!BT) {
            int br = tid >> 4, bc = (tid & 15) * 4;
            float4 bv = *(const float4*)(Bm + (size_t)(k0 + br) * N + col0 + bc);
            if (BSC) {
                float s = bscale[k0 + br];
                bv.x *= s; bv.y *= s; bv.z *= s; bv.w *= s;
            }
            *(float4*)&Bs[br][bc] = bv;
        } else {
            int n = tid >> 2, kk = (tid & 3) * 4;
            float4 bv = *(const float4*)(Bm + (size_t)(col0 + n) * Kd + k0 + kk);
            Bs[kk + 0][n] = bv.x; Bs[kk + 1][n] = bv.y;
            Bs[kk + 2][n] = bv.z; Bs[kk + 3][n] = bv.w;
        }
        __syncthreads();
#pragma unroll
        for (int kk = 0; kk < 16; ++kk) {
            float a[4], b[4];
            *(float4*)a = *(const float4*)&As[kk][ty * 4];
            *(float4*)b = *(const float4*)&Bs[kk][tx * 4];
#pragma unroll
            for (int i = 0; i < 4; ++i)
#pragma unroll
                for (int j = 0; j < 4; ++j)
                    acc[i][j] = fmaf(a[i], b[j], acc[i][j]);
        }
        __syncthreads();
    }

#pragma unroll
    for (int i = 0; i < 4; ++i) {
        int r = row0 + ty * 4 + i;
        float4 v; float* vp = (float*)&v;
#pragma unroll
        for (int j = 0; j < 4; ++j) {
            int c = col0 + tx * 4 + j;
            float z = acc[i][j];
            if (bias) z += bias[c];
            if (EPI == 1) z = fmaxf(z, 0.0f);
            else if (EPI == 2) z = 1.0f / (1.0f + expf(-z));
            else if (EPI == 3) z = (z + 1.0f) * 0.5f;
            if (RSC) z *= rowscale[r];
            vp[j] = z;
        }
        *(float4*)(C + (size_t)r * N + col0 + tx * 4) = v;
    }
}

// ---------------------------------------------------------------------------
// Distance + argmin: scores = bbn @ ctx^T; d = cnorm[k] - 2*score; argmin per
// row with first-index tie-break via u64 key (monotone-float<<32 | idx).
// ---------------------------------------------------------------------------
__device__ inline unsigned long long shflxor_u64_w16(unsigned long long v, int mask) {
    unsigned int lo = (unsigned int)v, hi = (unsigned int)(v >> 32);
    lo = (unsigned int)__shfl_xor((int)lo, mask, 16);
    hi = (unsigned int)__shfl_xor((int)hi, mask, 16);
    return ((unsigned long long)hi << 32) | lo;
}

__global__ __launch_bounds__(256)
void dist_argmin(const float* __restrict__ A, const float* __restrict__ Bm,
                 const float* __restrict__ cnorm,
                 unsigned long long* __restrict__ argred, int M, int N, int Kd) {
    __shared__ float As[16][68];
    __shared__ float Bs[16][68];
    const int tid = threadIdx.x;
    const int tx = tid & 15, ty = tid >> 4;
    const int row0 = blockIdx.y * 64, col0 = blockIdx.x * 64;
    float acc[4][4] = {};

    for (int k0 = 0; k0 < Kd; k0 += 16) {
        int r = tid >> 2, kk = (tid & 3) * 4;
        float4 av = *(const float4*)(A + (size_t)(row0 + r) * Kd + k0 + kk);
        As[kk + 0][r] = av.x; As[kk + 1][r] = av.y;
        As[kk + 2][r] = av.z; As[kk + 3][r] = av.w;
        float4 bv = *(const float4*)(Bm + (size_t)(col0 + r) * Kd + k0 + kk);
        Bs[kk + 0][r] = bv.x; Bs[kk + 1][r] = bv.y;
        Bs[kk + 2][r] = bv.z; Bs[kk + 3][r] = bv.w;
        __syncthreads();
#pragma unroll
        for (int kk2 = 0; kk2 < 16; ++kk2) {
            float a[4], b[4];
            *(float4*)a = *(const float4*)&As[kk2][ty * 4];
            *(float4*)b = *(const float4*)&Bs[kk2][tx * 4];
#pragma unroll
            for (int i = 0; i < 4; ++i)
#pragma unroll
                for (int j = 0; j < 4; ++j)
                    acc[i][j] = fmaf(a[i], b[j], acc[i][j]);
        }
        __syncthreads();
    }

#pragma unroll
    for (int i = 0; i < 4; ++i) {
        int grow = row0 + ty * 4 + i;
        unsigned long long best = 0xFFFFFFFFFFFFFFFFull;
#pragma unroll
        for (int j = 0; j < 4; ++j) {
            int gcol = col0 + tx * 4 + j;
            float d = cnorm[gcol] - 2.0f * acc[i][j];
            unsigned int u = __float_as_uint(d);
            u = (u & 0x80000000u) ? ~u : (u | 0x80000000u);
            unsigned long long key = ((unsigned long long)u << 32) | (unsigned int)gcol;
            if (key < best) best = key;
        }
        // reduce across the 16 tx lanes (same ty -> same 16-lane group)
        for (int off = 8; off >= 1; off >>= 1) {
            unsigned long long o = shflxor_u64_w16(best, off);
            if (o < best) best = o;
        }
        if (tx == 0) atomicMin(&argred[grow], best);
    }
}

// ---------------------------------------------------------------------------
// Small helpers
// ---------------------------------------------------------------------------
__global__ void rowsumsq(const float* __restrict__ Mx, float* __restrict__ outv, int cols) {
    int row = blockIdx.x, t = threadIdx.x;  // 64 threads
    const float4* p = (const float4*)(Mx + (size_t)row * cols);
    float s = 0.f;
    for (int i = t; i < cols / 4; i += 64) {
        float4 v = p[i];
        s += v.x * v.x + v.y * v.y + v.z * v.z + v.w * v.w;
    }
    for (int off = 32; off >= 1; off >>= 1) s += __shfl_xor(s, off, 64);
    if (t == 0) outv[row] = s;
}

__global__ void gather_vn_onehot(const unsigned long long* __restrict__ argred,
                                 const float* __restrict__ ctx,
                                 float* __restrict__ vn, float* __restrict__ out_ci,
                                 int Lc, int Kc) {
    int row = blockIdx.x, t = threadIdx.x;  // 64 threads
    unsigned int idx = (unsigned int)(argred[row] & 0xFFFFFFFFull);
    const float4* c4 = (const float4*)(ctx + (size_t)idx * Lc);
    float4 v0 = c4[t], v1 = c4[t + 64];  // Lc=512 -> 128 float4
    float s = v0.x * v0.x + v0.y * v0.y + v0.z * v0.z + v0.w * v0.w
            + v1.x * v1.x + v1.y * v1.y + v1.z * v1.z + v1.w * v1.w;
    for (int off = 32; off >= 1; off >>= 1) s += __shfl_xor(s, off, 64);
    float inv = rsqrtf(s + 1e-8f);
    v0.x *= inv; v0.y *= inv; v0.z *= inv; v0.w *= inv;
    v1.x *= inv; v1.y *= inv; v1.z *= inv; v1.w *= inv;
    float4* o = (float4*)(vn + (size_t)row * Lc);
    o[t] = v0; o[t + 64] = v1;
    if (t == 0) out_ci[(size_t)row * Kc + idx] = 1.0f;
}

__global__ void colsum256(const float* __restrict__ vn, float* __restrict__ Svec,
                          int cols) {
    int col = blockIdx.x * 256 + threadIdx.x;
    int r0 = blockIdx.y * 256;
    float s = 0.f;
    for (int r = r0; r < r0 + 256; ++r) s += vn[(size_t)r * cols + col];
    atomicAdd(&Svec[col], s);
}

__global__ void dinv_k(const float* __restrict__ vn, const float* __restrict__ Svec,
                       float* __restrict__ dinv, int cols, int rowsB) {
    int row = blockIdx.x, t = threadIdx.x;  // 64 threads
    const float4* a = (const float4*)(vn + (size_t)row * cols);
    const float4* b = (const float4*)Svec;
    float s = 0.f;
    for (int i = t; i < cols / 4; i += 64) {
        float4 x = a[i], y = b[i];
        s += x.x * y.x + x.y * y.y + x.z * y.z + x.w * y.w;
    }
    for (int off = 32; off >= 1; off >>= 1) s += __shfl_xor(s, off, 64);
    if (t == 0) dinv[row] = rsqrtf(0.5f * (s + (float)rowsB) + 1e-8f);
}

// ---------------------------------------------------------------------------
extern "C" void kernel_launch(void* const* d_in, const int* in_sizes, int n_in,
                              void* d_out, int out_size, void* d_ws, size_t ws_size,
                              hipStream_t stream) {
    const float* x      = (const float*)d_in[0];
    const float* W_enc  = (const float*)d_in[1];
    const float* b_enc  = (const float*)d_in[2];
    const float* W_fc1  = (const float*)d_in[3];
    const float* b_fc1  = (const float*)d_in[4];
    const float* W_fc2  = (const float*)d_in[5];
    const float* b_fc2  = (const float*)d_in[6];
    const float* ctx    = (const float*)d_in[7];
    const float* W_gcn  = (const float*)d_in[8];
    const float* b_gcn  = (const float*)d_in[9];
    const float* W_dec1 = (const float*)d_in[10];
    const float* b_dec1 = (const float*)d_in[11];
    const float* W_dec2 = (const float*)d_in[12];
    const float* b_dec2 = (const float*)d_in[13];

    float* out = (float*)d_out;
    float* out_dec  = out;                                   // [B,F]
    float* out_bbn  = out_dec + (size_t)cB * cF;             // [B,L]
    float* out_ci   = out_bbn + (size_t)cB * cL;             // [B,K]
    float* out_feat = out_ci  + (size_t)cB * cK;             // [B,H]
    float* out_adj  = out_feat + (size_t)cB * cH;            // [B,B]

    float* wsf = (float*)d_ws;
    const size_t BL = (size_t)cB * cL;
    float* vn     = wsf;                       // [B,L]
    float* cbn    = vn + BL;                   // [B,L]
    float* tbuf   = cbn + BL;                  // [B,L]
    float* latent = tbuf + BL;                 // [B,L]
    float* h1     = latent + BL;               // [B,H]
    float* cnorm  = h1 + (size_t)cB * cH;      // [K]
    float* Svec   = cnorm + cK;                // [L]
    float* dinvp  = Svec + cL;                 // [B]
    unsigned long long* argred = (unsigned long long*)(dinvp + cB);  // [B] u64

    dim3 blk(256);

    // init (out/ws are poisoned before every launch)
    hipMemsetAsync(out_ci, 0, (size_t)cB * cK * sizeof(float), stream);
    hipMemsetAsync(argred, 0xFF, (size_t)cB * sizeof(unsigned long long), stream);
    hipMemsetAsync(Svec, 0, cL * sizeof(float), stream);

    // feat = relu(x @ W_enc + b_enc)  -> out_feat
    gemm_f32<1, false, false, false><<<dim3(cH / 64, cB / 64), blk, 0, stream>>>(
        x, W_enc, b_enc, nullptr, nullptr, out_feat, cB, cH, cF);

    // bbn = feat @ W_fc1 + b_fc1 -> out_bbn
    gemm_f32<0, false, false, false><<<dim3(cL / 64, cB / 64), blk, 0, stream>>>(
        out_feat, W_fc1, b_fc1, nullptr, nullptr, out_bbn, cB, cL, cH);

    // cbn = feat @ W_fc2 + b_fc2 -> ws
    gemm_f32<0, false, false, false><<<dim3(cL / 64, cB / 64), blk, 0, stream>>>(
        out_feat, W_fc2, b_fc2, nullptr, nullptr, cbn, cB, cL, cH);

    // cnorm[k] = ||context_k||^2
    rowsumsq<<<cK, 64, 0, stream>>>(ctx, cnorm, cL);

    // argmin_k ( cnorm[k] - 2 * bbn . ctx_k )
    dist_argmin<<<dim3(cK / 64, cB / 64), blk, 0, stream>>>(
        out_bbn, ctx, cnorm, argred, cB, cK, cL);

    // quant gather, normalize -> vn; one-hot scatter -> out_ci
    gather_vn_onehot<<<cB, 64, 0, stream>>>(argred, ctx, vn, out_ci, cL, cK);

    // Svec = column sums of vn
    colsum256<<<dim3(cL / 256, cB / 256), blk, 0, stream>>>(vn, Svec, cL);

    // adj = (vn @ vn^T + 1) * 0.5 -> out_adj
    gemm_f32<3, true, false, false><<<dim3(cB / 64, cB / 64), blk, 0, stream>>>(
        vn, vn, nullptr, nullptr, nullptr, out_adj, cB, cB, cL);

    // dinv[i] = rsqrt(0.5*(vn_i . Svec + B) + 1e-8)
    dinv_k<<<cB, 64, 0, stream>>>(vn, Svec, dinvp, cL, cB);

    // t = dinv[i] * (adj @ (dinv[j] * cbn))
    gemm_f32<0, false, true, true><<<dim3(cL / 64, cB / 64), blk, 0, stream>>>(
        out_adj, cbn, nullptr, dinvp, dinvp, tbuf, cB, cL, cB);

    // latent = sigmoid(t @ W_gcn + b_gcn)
    gemm_f32<2, false, false, false><<<dim3(cL / 64, cB / 64), blk, 0, stream>>>(
        tbuf, W_gcn, b_gcn, nullptr, nullptr, latent, cB, cL, cL);

    // h1 = relu(latent @ W_dec1 + b_dec1)
    gemm_f32<1, false, false, false><<<dim3(cH / 64, cB / 64), blk, 0, stream>>>(
        latent, W_dec1, b_dec1, nullptr, nullptr, h1, cB, cH, cL);

    // decoded = h1 @ W_dec2 + b_dec2 -> out_dec
    gemm_f32<0, false, false, false><<<dim3(cF / 64, cB / 64), blk, 0, stream>>>(
        h1, W_dec2, b_dec2, nullptr, nullptr, out_dec, cB, cF, cH);
}

// Round 2
// 1250.980 us; speedup vs baseline: 1.9171x; 1.9171x over previous
//
#include <hip/hip_runtime.h>
#include <hip/hip_bf16.h>
#include <stdint.h>

using u32 = unsigned int;
using u64 = unsigned long long;
using bf16 = __hip_bfloat16;
typedef __attribute__((ext_vector_type(8))) short short8;
typedef __attribute__((ext_vector_type(4))) float f32x4;

constexpr int cB = 4096;   // batch
constexpr int cF = 4096;   // feat dim
constexpr int cH = 1024;   // enc hidden
constexpr int cL = 512;    // latent
constexpr int cK = 8192;   // codebook size
constexpr float MARGIN = 0.02f;  // >> max coarse bf16 distance error (~2.5e-3)

// monotone float->u32 key (ascending order preserved)
__device__ inline u32 monoKey(float d) {
    u32 u = __float_as_uint(d);
    return (u & 0x80000000u) ? ~u : (u | 0x80000000u);
}
__device__ inline float keyToFloat(u32 k) {
    u32 u = (k & 0x80000000u) ? (k ^ 0x80000000u) : ~k;
    return __uint_as_float(u);
}

__device__ inline u64 shflxor_u64_w16(u64 v, int mask) {
    u32 lo = (u32)v, hi = (u32)(v >> 32);
    lo = (u32)__shfl_xor((int)lo, mask, 16);
    hi = (u32)__shfl_xor((int)hi, mask, 16);
    return ((u64)hi << 32) | lo;
}

// ---------------------------------------------------------------------------
// fp32 tiled GEMM (strict chain: feat, bbn). 64x64 tile, BK=16, 4x4 micro.
// EPI: 0=none, 1=relu
// ---------------------------------------------------------------------------
template<int EPI>
__global__ __launch_bounds__(256)
void gemm_f32(const float* __restrict__ A, const float* __restrict__ Bm,
              const float* __restrict__ bias, float* __restrict__ C,
              int N, int Kd) {
    __shared__ float As[16][68];
    __shared__ float Bs[16][68];
    const int tid = threadIdx.x;
    const int tx = tid & 15, ty = tid >> 4;
    const int row0 = blockIdx.y * 64, col0 = blockIdx.x * 64;
    float acc[4][4] = {};

    for (int k0 = 0; k0 < Kd; k0 += 16) {
        {
            int r = tid >> 2, kk = (tid & 3) * 4;
            float4 av = *(const float4*)(A + (size_t)(row0 + r) * Kd + k0 + kk);
            As[kk + 0][r] = av.x; As[kk + 1][r] = av.y;
            As[kk + 2][r] = av.z; As[kk + 3][r] = av.w;
        }
        {
            int br = tid >> 4, bc = (tid & 15) * 4;
            float4 bv = *(const float4*)(Bm + (size_t)(k0 + br) * N + col0 + bc);
            *(float4*)&Bs[br][bc] = bv;
        }
        __syncthreads();
#pragma unroll
        for (int kk = 0; kk < 16; ++kk) {
            float a[4], b[4];
            *(float4*)a = *(const float4*)&As[kk][ty * 4];
            *(float4*)b = *(const float4*)&Bs[kk][tx * 4];
#pragma unroll
            for (int i = 0; i < 4; ++i)
#pragma unroll
                for (int j = 0; j < 4; ++j)
                    acc[i][j] = fmaf(a[i], b[j], acc[i][j]);
        }
        __syncthreads();
    }

#pragma unroll
    for (int i = 0; i < 4; ++i) {
        int r = row0 + ty * 4 + i;
        float4 v; float* vp = (float*)&v;
#pragma unroll
        for (int j = 0; j < 4; ++j) {
            int c = col0 + tx * 4 + j;
            float z = acc[i][j] + bias[c];
            if (EPI == 1) z = fmaxf(z, 0.0f);
            vp[j] = z;
        }
        *(float4*)(C + (size_t)r * N + col0 + tx * 4) = v;
    }
}

// ---------------------------------------------------------------------------
// bf16 MFMA GEMM core. Tile BM x 128, BK=32, 256 threads = 4 waves (2x2),
// wave tile (BM/2) x 64, mfma_f32_16x16x32_bf16.
// A is [M,K] row-major, Bt is [N,K] row-major (i.e. B transposed).
// AF32/BF32: operand stored fp32 in global; converted to bf16 during staging.
// ---------------------------------------------------------------------------
template<int BM, bool AF32, bool BF32>
__device__ inline void stage_tile(const void* A, const void* Bt, int K, int k0,
                                  int row0, int col0, bf16* sm, int tid) {
    constexpr int CA = BM * 4;             // 16B chunks for A
    constexpr int TOT = CA + 512;          // + B chunks (128 rows * 4)
#pragma unroll
    for (int j = 0; j < TOT / 256; ++j) {
        int c = j * 256 + tid;
        bf16* dst = sm + c * 8;
        bool isA = (c < CA);
        int cc = isA ? c : c - CA;
        int r = cc >> 2, kof = (cc & 3) * 8;
        int grow = isA ? (row0 + r) : (col0 + r);
        size_t eoff = (size_t)grow * K + k0 + kof;
        bool f32 = isA ? AF32 : BF32;
        if (f32) {
            const float* s = (const float*)(isA ? A : Bt) + eoff;
            float4 f0 = *(const float4*)s;
            float4 f1 = *(const float4*)(s + 4);
            union { short8 v; bf16 h[8]; } u;
            u.h[0] = __float2bfloat16(f0.x); u.h[1] = __float2bfloat16(f0.y);
            u.h[2] = __float2bfloat16(f0.z); u.h[3] = __float2bfloat16(f0.w);
            u.h[4] = __float2bfloat16(f1.x); u.h[5] = __float2bfloat16(f1.y);
            u.h[6] = __float2bfloat16(f1.z); u.h[7] = __float2bfloat16(f1.w);
            *(short8*)dst = u.v;
        } else {
            const bf16* s = (const bf16*)(isA ? A : Bt) + eoff;
            *(short8*)dst = *(const short8*)s;
        }
    }
}

// EPI: 0=none, 1=relu, 2=sigmoid, 3=(x+1)*0.5
template<int BM, int EPI, bool AF32, bool BF32, bool BIAS, bool RSC, bool OF32, bool OB16>
__global__ __launch_bounds__(256)
void gemm_bf(const void* __restrict__ A, const void* __restrict__ Bt,
             const float* __restrict__ bias, const float* __restrict__ rsc,
             float* __restrict__ Cf, bf16* __restrict__ Cb, int N, int K) {
    constexpr int MT = BM / 32;
    __shared__ bf16 sm[(BM + 128) * 32];
    bf16* smB = sm + BM * 32;
    const int tid = threadIdx.x;
    const int wid = tid >> 6, lane = tid & 63;
    const int wm = wid >> 1, wn = wid & 1;
    const int row0 = blockIdx.y * BM, col0 = blockIdx.x * 128;
    const int lr = lane & 15, lq = lane >> 4;

    f32x4 acc[MT][4];
#pragma unroll
    for (int mt = 0; mt < MT; ++mt)
#pragma unroll
        for (int nt = 0; nt < 4; ++nt)
            acc[mt][nt] = (f32x4){0.f, 0.f, 0.f, 0.f};

    for (int k0 = 0; k0 < K; k0 += 32) {
        stage_tile<BM, AF32, BF32>(A, Bt, K, k0, row0, col0, sm, tid);
        __syncthreads();
        short8 af[MT], bfr[4];
#pragma unroll
        for (int mt = 0; mt < MT; ++mt) {
            int rit = wm * (BM / 2) + mt * 16 + lr;
            af[mt] = *(const short8*)(sm + rit * 32 + lq * 8);
        }
#pragma unroll
        for (int nt = 0; nt < 4; ++nt) {
            int nit = wn * 64 + nt * 16 + lr;
            bfr[nt] = *(const short8*)(smB + nit * 32 + lq * 8);
        }
#pragma unroll
        for (int mt = 0; mt < MT; ++mt)
#pragma unroll
            for (int nt = 0; nt < 4; ++nt)
                acc[mt][nt] = __builtin_amdgcn_mfma_f32_16x16x32_bf16(
                    af[mt], bfr[nt], acc[mt][nt], 0, 0, 0);
        __syncthreads();
    }

#pragma unroll
    for (int mt = 0; mt < MT; ++mt) {
#pragma unroll
        for (int nt = 0; nt < 4; ++nt) {
            int col = col0 + wn * 64 + nt * 16 + lr;
            float bv = BIAS ? bias[col] : 0.0f;
#pragma unroll
            for (int r = 0; r < 4; ++r) {
                int row = row0 + wm * (BM / 2) + mt * 16 + lq * 4 + r;
                float z = acc[mt][nt][r] + bv;
                if (EPI == 1) z = fmaxf(z, 0.0f);
                else if (EPI == 2) z = 1.0f / (1.0f + expf(-z));
                else if (EPI == 3) z = (z + 1.0f) * 0.5f;
                if (RSC) z *= rsc[row];
                if (OF32) Cf[(size_t)row * N + col] = z;
                if (OB16) Cb[(size_t)row * N + col] = __float2bfloat16(z);
            }
        }
    }
}

// ---------------------------------------------------------------------------
// Coarse distance GEMM (bf16) with per-row per-64-col top-2 key output.
// d = cnorm[col] - 2 * (bbn . ctx_col). key = mono(d)<<32 | col.
// topbuf layout: [row][N/64][2] u64.
// ---------------------------------------------------------------------------
__global__ __launch_bounds__(256)
void gemm_dist(const float* __restrict__ A, const float* __restrict__ Bt,
               const float* __restrict__ cnorm, u64* __restrict__ topbuf,
               int N, int K) {
    constexpr int MT = 4;
    __shared__ bf16 sm[(128 + 128) * 32];
    bf16* smB = sm + 128 * 32;
    const int tid = threadIdx.x;
    const int wid = tid >> 6, lane = tid & 63;
    const int wm = wid >> 1, wn = wid & 1;
    const int row0 = blockIdx.y * 128, col0 = blockIdx.x * 128;
    const int lr = lane & 15, lq = lane >> 4;

    f32x4 acc[MT][4];
#pragma unroll
    for (int mt = 0; mt < MT; ++mt)
#pragma unroll
        for (int nt = 0; nt < 4; ++nt)
            acc[mt][nt] = (f32x4){0.f, 0.f, 0.f, 0.f};

    for (int k0 = 0; k0 < K; k0 += 32) {
        stage_tile<128, true, true>(A, Bt, K, k0, row0, col0, sm, tid);
        __syncthreads();
        short8 af[MT], bfr[4];
#pragma unroll
        for (int mt = 0; mt < MT; ++mt) {
            int rit = wm * 64 + mt * 16 + lr;
            af[mt] = *(const short8*)(sm + rit * 32 + lq * 8);
        }
#pragma unroll
        for (int nt = 0; nt < 4; ++nt) {
            int nit = wn * 64 + nt * 16 + lr;
            bfr[nt] = *(const short8*)(smB + nit * 32 + lq * 8);
        }
#pragma unroll
        for (int mt = 0; mt < MT; ++mt)
#pragma unroll
            for (int nt = 0; nt < 4; ++nt)
                acc[mt][nt] = __builtin_amdgcn_mfma_f32_16x16x32_bf16(
                    af[mt], bfr[nt], acc[mt][nt], 0, 0, 0);
        __syncthreads();
    }

    const int nhalves = N >> 6;
    const int half = blockIdx.x * 2 + wn;
    float cn[4];
#pragma unroll
    for (int nt = 0; nt < 4; ++nt)
        cn[nt] = cnorm[col0 + wn * 64 + nt * 16 + lr];

#pragma unroll
    for (int mt = 0; mt < 4; ++mt) {
#pragma unroll
        for (int r = 0; r < 4; ++r) {
            int row = row0 + wm * 64 + mt * 16 + lq * 4 + r;
            u64 k0v = ~0ull, k1v = ~0ull;
#pragma unroll
            for (int nt = 0; nt < 4; ++nt) {
                int col = col0 + wn * 64 + nt * 16 + lr;
                float d = cn[nt] - 2.0f * acc[mt][nt][r];
                u64 kk = ((u64)monoKey(d) << 32) | (u32)col;
                if (kk < k0v) { k1v = k0v; k0v = kk; }
                else if (kk < k1v) k1v = kk;
            }
#pragma unroll
            for (int m = 1; m <= 8; m <<= 1) {
                u64 o0 = shflxor_u64_w16(k0v, m);
                u64 o1 = shflxor_u64_w16(k1v, m);
                u64 n0 = k0v < o0 ? k0v : o0;
                u64 hi = k0v < o0 ? o0 : k0v;
                u64 lo2 = k1v < o1 ? k1v : o1;
                k0v = n0;
                k1v = hi < lo2 ? hi : lo2;
            }
            if (lr == 0) {
                u64* p = topbuf + ((size_t)row * nhalves + half) * 2;
                p[0] = k0v; p[1] = k1v;
            }
        }
    }
}

// Resolve: block per row. Find global coarse min over 256 candidate keys,
// exact-rescore (fp32) every candidate within MARGIN, atomicMin exact key.
__global__ __launch_bounds__(256)
void dist_resolve(const u64* __restrict__ topbuf, const float* __restrict__ bbn,
                  const float* __restrict__ ctx, const float* __restrict__ cnorm,
                  u64* __restrict__ argred) {
    int row = blockIdx.x, t = threadIdx.x;
    u64 my = topbuf[(size_t)row * 256 + t];
    __shared__ u64 red[256];
    red[t] = my;
    __syncthreads();
    for (int s = 128; s > 0; s >>= 1) {
        if (t < s) { u64 o = red[t + s]; if (o < red[t]) red[t] = o; }
        __syncthreads();
    }
    float bestd = keyToFloat((u32)(red[0] >> 32));
    float thr = bestd + MARGIN;
    float myd = keyToFloat((u32)(my >> 32));
    if (myd <= thr) {
        int idx = (int)(my & 0xFFFFFFFFu);
        const float4* b4 = (const float4*)(bbn + (size_t)row * cL);
        const float4* c4 = (const float4*)(ctx + (size_t)idx * cL);
        float s = 0.f;
        for (int i = 0; i < cL / 4; ++i) {
            float4 x = b4[i], y = c4[i];
            s = fmaf(x.x, y.x, s); s = fmaf(x.y, y.y, s);
            s = fmaf(x.z, y.z, s); s = fmaf(x.w, y.w, s);
        }
        float ex = cnorm[idx] - 2.0f * s;
        u64 k = ((u64)monoKey(ex) << 32) | (u32)idx;
        atomicMin(&argred[row], k);
    }
}

// ---------------------------------------------------------------------------
// Small helpers
// ---------------------------------------------------------------------------
__global__ void rowsumsq(const float* __restrict__ Mx, float* __restrict__ outv, int cols) {
    int row = blockIdx.x, t = threadIdx.x;  // 64 threads
    const float4* p = (const float4*)(Mx + (size_t)row * cols);
    float s = 0.f;
    for (int i = t; i < cols / 4; i += 64) {
        float4 v = p[i];
        s += v.x * v.x + v.y * v.y + v.z * v.z + v.w * v.w;
    }
    for (int off = 32; off >= 1; off >>= 1) s += __shfl_xor(s, off, 64);
    if (t == 0) outv[row] = s;
}

// transpose + fp32->bf16 convert (+ optional input-row scale): out[c][r] = in[r][c]*s[r]
__global__ __launch_bounds__(256)
void transpose_cvt(const float* __restrict__ in, bf16* __restrict__ out,
                   const float* __restrict__ scale, int R, int C) {
    __shared__ float tile[32][33];
    int c0 = blockIdx.x * 32, r0 = blockIdx.y * 32;
    int tx = threadIdx.x & 31, ty = threadIdx.x >> 5;
#pragma unroll
    for (int i = 0; i < 4; ++i) {
        int rr = ty + i * 8;
        int r = r0 + rr;
        float v = in[(size_t)r * C + c0 + tx];
        if (scale) v *= scale[r];
        tile[rr][tx] = v;
    }
    __syncthreads();
#pragma unroll
    for (int i = 0; i < 4; ++i) {
        int a = ty + i * 8;
        out[(size_t)(c0 + a) * R + r0 + tx] = __float2bfloat16(tile[tx][a]);
    }
}

// gather quantized code, normalize -> vnb (bf16); scatter one-hot
__global__ void gather_vn(const u64* __restrict__ argred, const float* __restrict__ ctx,
                          bf16* __restrict__ vnb, float* __restrict__ out_ci) {
    int row = blockIdx.x, t = threadIdx.x;  // 64 threads
    u32 idx = (u32)(argred[row] & 0xFFFFFFFFull);
    const float4* c4 = (const float4*)(ctx + (size_t)idx * cL);
    float4 v0 = c4[2 * t], v1 = c4[2 * t + 1];
    float s = v0.x * v0.x + v0.y * v0.y + v0.z * v0.z + v0.w * v0.w
            + v1.x * v1.x + v1.y * v1.y + v1.z * v1.z + v1.w * v1.w;
    for (int off = 32; off >= 1; off >>= 1) s += __shfl_xor(s, off, 64);
    float inv = rsqrtf(s + 1e-8f);
    union { short8 v; bf16 h[8]; } u;
    u.h[0] = __float2bfloat16(v0.x * inv); u.h[1] = __float2bfloat16(v0.y * inv);
    u.h[2] = __float2bfloat16(v0.z * inv); u.h[3] = __float2bfloat16(v0.w * inv);
    u.h[4] = __float2bfloat16(v1.x * inv); u.h[5] = __float2bfloat16(v1.y * inv);
    u.h[6] = __float2bfloat16(v1.z * inv); u.h[7] = __float2bfloat16(v1.w * inv);
    *(short8*)(vnb + (size_t)row * cL + t * 8) = u.v;
    if (t == 0) out_ci[(size_t)row * cK + idx] = 1.0f;
}

__global__ void colsum_b(const bf16* __restrict__ vnb, float* __restrict__ Svec) {
    int col = blockIdx.x * 256 + threadIdx.x;
    int r0 = blockIdx.y * 256;
    float s = 0.f;
    for (int r = r0; r < r0 + 256; ++r) s += __bfloat162float(vnb[(size_t)r * cL + col]);
    atomicAdd(&Svec[col], s);
}

__global__ void dinv_b(const bf16* __restrict__ vnb, const float* __restrict__ Svec,
                       float* __restrict__ dinv) {
    int row = blockIdx.x, t = threadIdx.x;  // 64 threads
    float s = 0.f;
#pragma unroll
    for (int i = 0; i < 8; ++i) {
        int c = t * 8 + i;
        s += __bfloat162float(vnb[(size_t)row * cL + c]) * Svec[c];
    }
    for (int off = 32; off >= 1; off >>= 1) s += __shfl_xor(s, off, 64);
    if (t == 0) dinv[row] = rsqrtf(0.5f * (s + (float)cB) + 1e-8f);
}

// ---------------------------------------------------------------------------
extern "C" void kernel_launch(void* const* d_in, const int* in_sizes, int n_in,
                              void* d_out, int out_size, void* d_ws, size_t ws_size,
                              hipStream_t stream) {
    const float* x      = (const float*)d_in[0];
    const float* W_enc  = (const float*)d_in[1];
    const float* b_enc  = (const float*)d_in[2];
    const float* W_fc1  = (const float*)d_in[3];
    const float* b_fc1  = (const float*)d_in[4];
    const float* W_fc2  = (const float*)d_in[5];
    const float* b_fc2  = (const float*)d_in[6];
    const float* ctx    = (const float*)d_in[7];
    const float* W_gcn  = (const float*)d_in[8];
    const float* b_gcn  = (const float*)d_in[9];
    const float* W_dec1 = (const float*)d_in[10];
    const float* b_dec1 = (const float*)d_in[11];
    const float* W_dec2 = (const float*)d_in[12];
    const float* b_dec2 = (const float*)d_in[13];

    float* out = (float*)d_out;
    float* out_dec  = out;                                   // [B,F]
    float* out_bbn  = out_dec + (size_t)cB * cF;             // [B,L]
    float* out_ci   = out_bbn + (size_t)cB * cL;             // [B,K]
    float* out_feat = out_ci  + (size_t)cB * cK;             // [B,H]
    float* out_adj  = out_feat + (size_t)cB * cH;            // [B,B]

    char* p = (char*)d_ws;
    auto alloc = [&](size_t n) { void* r = p; p += (n + 255) & ~(size_t)255; return r; };
    float* cnorm  = (float*)alloc((size_t)cK * 4);
    float* Svec   = (float*)alloc((size_t)cL * 4);
    float* dinvp  = (float*)alloc((size_t)cB * 4);
    u64* argred   = (u64*)alloc((size_t)cB * 8);
    u64* topbuf   = (u64*)alloc((size_t)cB * 256 * 8);        // [B][128][2]
    bf16* W_fc2t  = (bf16*)alloc((size_t)cL * cH * 2);
    bf16* W_gcnt  = (bf16*)alloc((size_t)cL * cL * 2);
    bf16* W_dec1t = (bf16*)alloc((size_t)cH * cL * 2);
    bf16* W_dec2t = (bf16*)alloc((size_t)cF * cH * 2);
    bf16* vnb     = (bf16*)alloc((size_t)cB * cL * 2);
    float* cbn    = (float*)alloc((size_t)cB * cL * 4);
    bf16* cbnst   = (bf16*)alloc((size_t)cL * cB * 2);        // [L][B]
    bf16* tbufb   = (bf16*)alloc((size_t)cB * cL * 2);
    bf16* latentb = (bf16*)alloc((size_t)cB * cL * 2);
    bf16* h1b     = (bf16*)alloc((size_t)cB * cH * 2);

    dim3 blk(256);

    hipMemsetAsync(out_ci, 0, (size_t)cB * cK * sizeof(float), stream);
    hipMemsetAsync(argred, 0xFF, (size_t)cB * sizeof(u64), stream);
    hipMemsetAsync(Svec, 0, cL * sizeof(float), stream);

    // ---- strict fp32 chain ----
    gemm_f32<1><<<dim3(cH / 64, cB / 64), blk, 0, stream>>>(x, W_enc, b_enc, out_feat, cH, cF);
    gemm_f32<0><<<dim3(cL / 64, cB / 64), blk, 0, stream>>>(out_feat, W_fc1, b_fc1, out_bbn, cL, cH);

    // ---- prep: codebook norms, weight transposes ----
    rowsumsq<<<cK, 64, 0, stream>>>(ctx, cnorm, cL);
    transpose_cvt<<<dim3(cL / 32, cH / 32), blk, 0, stream>>>(W_fc2, W_fc2t, nullptr, cH, cL);
    transpose_cvt<<<dim3(cL / 32, cL / 32), blk, 0, stream>>>(W_gcn, W_gcnt, nullptr, cL, cL);
    transpose_cvt<<<dim3(cH / 32, cL / 32), blk, 0, stream>>>(W_dec1, W_dec1t, nullptr, cL, cH);
    transpose_cvt<<<dim3(cF / 32, cH / 32), blk, 0, stream>>>(W_dec2, W_dec2t, nullptr, cH, cF);

    // ---- coarse distances (bf16 MFMA) + exact argmin resolve ----
    gemm_dist<<<dim3(cK / 128, cB / 128), blk, 0, stream>>>(out_bbn, ctx, cnorm, topbuf, cK, cL);
    dist_resolve<<<cB, blk, 0, stream>>>(topbuf, out_bbn, ctx, cnorm, argred);

    // ---- quantize / normalize / one-hot ----
    gather_vn<<<cB, 64, 0, stream>>>(argred, ctx, vnb, out_ci);
    colsum_b<<<dim3(cL / 256, cB / 256), blk, 0, stream>>>(vnb, Svec);
    dinv_b<<<cB, 64, 0, stream>>>(vnb, Svec, dinvp);

    // ---- cbn = feat @ W_fc2 + b (bf16, A from fp32 feat) ----
    gemm_bf<64, 0, true, false, true, false, true, false>
        <<<dim3(cL / 128, cB / 64), blk, 0, stream>>>(out_feat, W_fc2t, b_fc2, nullptr, cbn, nullptr, cL, cH);

    // ---- adj = (vn @ vn^T + 1) * 0.5 ----
    gemm_bf<128, 3, false, false, false, false, true, false>
        <<<dim3(cB / 128, cB / 128), blk, 0, stream>>>(vnb, vnb, nullptr, nullptr, out_adj, nullptr, cB, cL);

    // ---- cbnst[l][j] = dinv[j] * cbn[j][l] (bf16 transposed) ----
    transpose_cvt<<<dim3(cL / 32, cB / 32), blk, 0, stream>>>(cbn, cbnst, dinvp, cB, cL);

    // ---- t = dinv[i] * (adj @ cbn_scaled)  (A from fp32 adj) ----
    gemm_bf<64, 0, true, false, false, true, false, true>
        <<<dim3(cL / 128, cB / 64), blk, 0, stream>>>(out_adj, cbnst, nullptr, dinvp, nullptr, tbufb, cL, cB);

    // ---- latent = sigmoid(t @ W_gcn + b_gcn) ----
    gemm_bf<64, 2, false, false, true, false, false, true>
        <<<dim3(cL / 128, cB / 64), blk, 0, stream>>>(tbufb, W_gcnt, b_gcn, nullptr, nullptr, latentb, cL, cL);

    // ---- h1 = relu(latent @ W_dec1 + b_dec1) ----
    gemm_bf<128, 1, false, false, true, false, false, true>
        <<<dim3(cH / 128, cB / 128), blk, 0, stream>>>(latentb, W_dec1t, b_dec1, nullptr, nullptr, h1b, cH, cL);

    // ---- decoded = h1 @ W_dec2 + b_dec2 ----
    gemm_bf<128, 0, false, false, true, false, true, false>
        <<<dim3(cF / 128, cB / 128), blk, 0, stream>>>(h1b, W_dec2t, b_dec2, nullptr, out_dec, nullptr, cF, cH);
}